// Round 3
// baseline (831.509 us; speedup 1.0000x reference)
//
#include <hip/hip_runtime.h>

#define ROWS  16384
#define PTOT  1048576
#define NTOTF 1048576.0f
#define EPSF  1e-5f
#define NREP  16                 // stats replication factor (atomic decontention)
#define NBLK  512                // persistent blocks: 2/CU guaranteed co-resident

typedef _Float16 half8  __attribute__((ext_vector_type(8)));   // MFMA A/B frag (4 VGPR)
typedef _Float16 half2v __attribute__((ext_vector_type(2)));
typedef __fp16   fp16x2 __attribute__((ext_vector_type(2)));   // cvt_pkrtz result type
typedef __attribute__((ext_vector_type(4))) float floatx4;     // MFMA C/D frag
typedef float f32x4 __attribute__((ext_vector_type(4)));
typedef f32x4 f32x4u __attribute__((aligned(4)));              // 4B-aligned vector load

union H8 { half8 v8; half2v v2[4]; };
union PK2 { fp16x2 p; half2v h; unsigned int u; };

__device__ __forceinline__ half2v cvt2(float lo, float hi) {
    PK2 k; k.p = __builtin_amdgcn_cvt_pkrtz(lo, hi); return k.h;
}
__device__ __forceinline__ unsigned int cvt2u(float lo, float hi) {
    PK2 k; k.p = __builtin_amdgcn_cvt_pkrtz(lo, hi); return k.u;
}
__device__ __forceinline__ float relu_f(float x) { return x > 0.f ? x : 0.f; }

__device__ __forceinline__ half8 h8zero() {
    half8 z = {(_Float16)0.f, (_Float16)0.f, (_Float16)0.f, (_Float16)0.f,
               (_Float16)0.f, (_Float16)0.f, (_Float16)0.f, (_Float16)0.f};
    return z;
}

// packed BN + ReLU: v_pk_fma_f16 + v_pk_max_f16
__device__ __forceinline__ half2v bn2(half2v h, half2v a, half2v b) {
    half2v z = {(_Float16)0.f, (_Float16)0.f};
    return __builtin_elementwise_max((half2v)(h * a + b), z);
}

__device__ __forceinline__ float aload(const float* p) {
    return __hip_atomic_load(p, __ATOMIC_RELAXED, __HIP_MEMORY_SCOPE_AGENT);
}

// classic two-step grid barrier; all NBLK blocks guaranteed co-resident
__device__ __forceinline__ void gridbar(unsigned int* cnt, unsigned int* flg) {
    __syncthreads();
    if (threadIdx.x == 0) {
        __threadfence();
        if (atomicAdd(cnt, 1u) == NBLK - 1u) {
            __threadfence();
            __hip_atomic_store(flg, 1u, __ATOMIC_RELEASE, __HIP_MEMORY_SCOPE_AGENT);
        } else {
            while (__hip_atomic_load(flg, __ATOMIC_ACQUIRE, __HIP_MEMORY_SCOPE_AGENT) == 0u)
                __builtin_amdgcn_s_sleep(8);
        }
    }
    __syncthreads();
}

// ---------------------------------------------------------------------------
// Fused persistent kernel: conv0 -> [grid bar] -> conv1 -> [grid bar] ->
// conv2(+rowmax/min in LDS) -> [grid bar] -> BN2 epilogue.
// Block b owns positions [b*2048, (b+1)*2048) in every phase -> H chunk is
// XCD-local (no cross-XCD H coherence needed); rowmax/min never touch HBM.
// Cross-block data: only the replicated stats array (atomicAdd writes,
// agent-scope atomic loads after each barrier).
// ---------------------------------------------------------------------------
__global__ __launch_bounds__(256, 2) void k_fused(
    const float* __restrict__ X,
    const float* __restrict__ w0, const float* __restrict__ b0,
    const float* __restrict__ g0, const float* __restrict__ be0,
    const float* __restrict__ w1, const float* __restrict__ b1,
    const float* __restrict__ g1, const float* __restrict__ be1,
    const float* __restrict__ w2, const float* __restrict__ cb2,
    const float* __restrict__ g2, const float* __restrict__ be2,
    const _Float16* __restrict__ Hin, _Float16* __restrict__ Hout,
    float* __restrict__ stats, unsigned int* __restrict__ bar,
    float* __restrict__ out)
{
    __shared__ float als[128], bls[128], sred[128], s2red[128];
    __shared__ float smx[32 * 128], smn[32 * 128];

    const int tid  = threadIdx.x;
    const int lane = tid & 63;
    const int wid  = tid >> 6;
    const int ln15 = lane & 15;
    const int quad = lane >> 4;
    const int blk  = blockIdx.x;
    const int rep  = (blk & (NREP - 1)) * 512;

    // ===================== phase 0: conv0 (67 -> 64) =====================
    if (tid < 64) { sred[tid] = 0.f; s2red[tid] = 0.f; }
    __syncthreads();

    {
        half8 afr[4][3];
        floatx4 bias[4];
#pragma unroll
        for (int mt = 0; mt < 4; ++mt) {
            const float* wr = w0 + (size_t)(mt * 16 + ln15) * 67;
#pragma unroll
            for (int kh = 0; kh < 2; ++kh) {
                f32x4u wa = *reinterpret_cast<const f32x4u*>(wr + kh * 32 + quad * 8);
                f32x4u wb = *reinterpret_cast<const f32x4u*>(wr + kh * 32 + quad * 8 + 4);
                H8 t;
                t.v2[0] = cvt2(wa[0], wa[1]);
                t.v2[1] = cvt2(wa[2], wa[3]);
                t.v2[2] = cvt2(wb[0], wb[1]);
                t.v2[3] = cvt2(wb[2], wb[3]);
                afr[mt][kh] = t.v8;
            }
            H8 t; t.v8 = h8zero();
            if (quad == 0) {
                f32x4u tv = *reinterpret_cast<const f32x4u*>(wr + 63);  // cols 63..66
                t.v2[0] = cvt2(tv[1], tv[2]);
                t.v2[1] = cvt2(tv[3], 0.f);
            }
            afr[mt][2] = t.v8;
            bias[mt] = *reinterpret_cast<const floatx4*>(b0 + mt * 16 + quad * 4);
        }

        float s[4][4] = {}, s2[4][4] = {};
        for (int it = 0; it < 8; ++it) {
            const int pbase = blk * 2048 + it * 256 + wid * 64;
#pragma unroll 2
            for (int nt = 0; nt < 4; ++nt) {
                const int pos = pbase + nt * 16 + ln15;
                const float* xr = X + (size_t)pos * 67;
                H8 B0, B1, BT;
                {
                    f32x4u xa = *reinterpret_cast<const f32x4u*>(xr + quad * 8);
                    f32x4u xb = *reinterpret_cast<const f32x4u*>(xr + quad * 8 + 4);
                    f32x4u xc = *reinterpret_cast<const f32x4u*>(xr + 32 + quad * 8);
                    f32x4u xd = *reinterpret_cast<const f32x4u*>(xr + 32 + quad * 8 + 4);
                    B0.v2[0] = cvt2(xa[0], xa[1]);
                    B0.v2[1] = cvt2(xa[2], xa[3]);
                    B0.v2[2] = cvt2(xb[0], xb[1]);
                    B0.v2[3] = cvt2(xb[2], xb[3]);
                    B1.v2[0] = cvt2(xc[0], xc[1]);
                    B1.v2[1] = cvt2(xc[2], xc[3]);
                    B1.v2[2] = cvt2(xd[0], xd[1]);
                    B1.v2[3] = cvt2(xd[2], xd[3]);
                    BT.v8 = h8zero();
                    if (quad == 0) {
                        f32x4u tv = *reinterpret_cast<const f32x4u*>(xr + 63);
                        BT.v2[0] = cvt2(tv[1], tv[2]);
                        BT.v2[1] = cvt2(tv[3], 0.f);
                    }
                }
#pragma unroll
                for (int mt = 0; mt < 4; ++mt) {
                    floatx4 c = bias[mt];   // bias constant along cols -> C-init
                    c = __builtin_amdgcn_mfma_f32_16x16x32_f16(afr[mt][0], B0.v8, c, 0, 0, 0);
                    c = __builtin_amdgcn_mfma_f32_16x16x32_f16(afr[mt][1], B1.v8, c, 0, 0, 0);
                    c = __builtin_amdgcn_mfma_f32_16x16x32_f16(afr[mt][2], BT.v8, c, 0, 0, 0);
                    s[mt][0] += c[0]; s2[mt][0] += c[0] * c[0];
                    s[mt][1] += c[1]; s2[mt][1] += c[1] * c[1];
                    s[mt][2] += c[2]; s2[mt][2] += c[2] * c[2];
                    s[mt][3] += c[3]; s2[mt][3] += c[3] * c[3];
                    uint2 o;
                    o.x = cvt2u(c[0], c[1]);
                    o.y = cvt2u(c[2], c[3]);
                    *reinterpret_cast<uint2*>(&Hout[(size_t)pos * 64 + mt * 16 + quad * 4]) = o;
                }
            }
        }
#pragma unroll
        for (int mt = 0; mt < 4; ++mt)
#pragma unroll
            for (int rg = 0; rg < 4; ++rg) {
                s[mt][rg]  += __shfl_xor(s[mt][rg], 1, 64);  s[mt][rg]  += __shfl_xor(s[mt][rg], 2, 64);
                s[mt][rg]  += __shfl_xor(s[mt][rg], 4, 64);  s[mt][rg]  += __shfl_xor(s[mt][rg], 8, 64);
                s2[mt][rg] += __shfl_xor(s2[mt][rg], 1, 64); s2[mt][rg] += __shfl_xor(s2[mt][rg], 2, 64);
                s2[mt][rg] += __shfl_xor(s2[mt][rg], 4, 64); s2[mt][rg] += __shfl_xor(s2[mt][rg], 8, 64);
            }
        if (ln15 == 0) {
#pragma unroll
            for (int mt = 0; mt < 4; ++mt)
#pragma unroll
                for (int rg = 0; rg < 4; ++rg) {
                    atomicAdd(&sred[mt * 16 + quad * 4 + rg], s[mt][rg]);
                    atomicAdd(&s2red[mt * 16 + quad * 4 + rg], s2[mt][rg]);
                }
        }
        __syncthreads();
        if (tid < 64) {
            unsafeAtomicAdd(&stats[rep + tid], sred[tid]);
            unsafeAtomicAdd(&stats[rep + 64 + tid], s2red[tid]);
        }
    }
    gridbar(&bar[0], &bar[1]);

    // ===================== phase 1: conv1 (64 -> 64) =====================
    if (tid < 64) {
        float ssum = 0.f, qsum = 0.f;
#pragma unroll
        for (int r = 0; r < NREP; ++r) {
            ssum += aload(&stats[r * 512 + tid]);
            qsum += aload(&stats[r * 512 + 64 + tid]);
        }
        const float mean = ssum * (1.f / NTOTF);
        const float var  = qsum * (1.f / NTOTF) - mean * mean;
        const float a    = g0[tid] / sqrtf(var + EPSF);
        als[tid] = a; bls[tid] = be0[tid] - mean * a;
        sred[tid] = 0.f; s2red[tid] = 0.f;
    }
    __syncthreads();

    {
        half2v ba2[8], bb2[8];
#pragma unroll
        for (int kh = 0; kh < 2; ++kh)
#pragma unroll
            for (int j2 = 0; j2 < 4; ++j2) {
                const int c0 = kh * 32 + quad * 8 + 2 * j2;
                half2v av = {(_Float16)als[c0], (_Float16)als[c0 + 1]};
                half2v bv = {(_Float16)bls[c0], (_Float16)bls[c0 + 1]};
                ba2[kh * 4 + j2] = av; bb2[kh * 4 + j2] = bv;
            }

        half8 afr[4][2];
        floatx4 bias[4];
#pragma unroll
        for (int mt = 0; mt < 4; ++mt) {
            const float* wr = w1 + (size_t)(mt * 16 + ln15) * 64;
#pragma unroll
            for (int kh = 0; kh < 2; ++kh) {
                f32x4 wa = *reinterpret_cast<const f32x4*>(wr + kh * 32 + quad * 8);
                f32x4 wb = *reinterpret_cast<const f32x4*>(wr + kh * 32 + quad * 8 + 4);
                H8 t;
                t.v2[0] = cvt2(wa[0], wa[1]);
                t.v2[1] = cvt2(wa[2], wa[3]);
                t.v2[2] = cvt2(wb[0], wb[1]);
                t.v2[3] = cvt2(wb[2], wb[3]);
                afr[mt][kh] = t.v8;
            }
            bias[mt] = *reinterpret_cast<const floatx4*>(b1 + mt * 16 + quad * 4);
        }

        float s[4][4] = {}, s2[4][4] = {};
        for (int it = 0; it < 8; ++it) {
            const int pbase = blk * 2048 + it * 256 + wid * 64;
#pragma unroll 2
            for (int nt = 0; nt < 4; ++nt) {
                const int pos = pbase + nt * 16 + ln15;
                H8 r0, r1;
                r0.v8 = *reinterpret_cast<const half8*>(&Hin[(size_t)pos * 64 + quad * 8]);
                r1.v8 = *reinterpret_cast<const half8*>(&Hin[(size_t)pos * 64 + 32 + quad * 8]);
                H8 f0, f1;
#pragma unroll
                for (int j2 = 0; j2 < 4; ++j2) {
                    f0.v2[j2] = bn2(r0.v2[j2], ba2[j2], bb2[j2]);
                    f1.v2[j2] = bn2(r1.v2[j2], ba2[4 + j2], bb2[4 + j2]);
                }
#pragma unroll
                for (int mt = 0; mt < 4; ++mt) {
                    floatx4 c = bias[mt];
                    c = __builtin_amdgcn_mfma_f32_16x16x32_f16(afr[mt][0], f0.v8, c, 0, 0, 0);
                    c = __builtin_amdgcn_mfma_f32_16x16x32_f16(afr[mt][1], f1.v8, c, 0, 0, 0);
                    s[mt][0] += c[0]; s2[mt][0] += c[0] * c[0];
                    s[mt][1] += c[1]; s2[mt][1] += c[1] * c[1];
                    s[mt][2] += c[2]; s2[mt][2] += c[2] * c[2];
                    s[mt][3] += c[3]; s2[mt][3] += c[3] * c[3];
                    uint2 o;
                    o.x = cvt2u(c[0], c[1]);
                    o.y = cvt2u(c[2], c[3]);
                    *reinterpret_cast<uint2*>(&Hout[(size_t)pos * 64 + mt * 16 + quad * 4]) = o;
                }
            }
        }
#pragma unroll
        for (int mt = 0; mt < 4; ++mt)
#pragma unroll
            for (int rg = 0; rg < 4; ++rg) {
                s[mt][rg]  += __shfl_xor(s[mt][rg], 1, 64);  s[mt][rg]  += __shfl_xor(s[mt][rg], 2, 64);
                s[mt][rg]  += __shfl_xor(s[mt][rg], 4, 64);  s[mt][rg]  += __shfl_xor(s[mt][rg], 8, 64);
                s2[mt][rg] += __shfl_xor(s2[mt][rg], 1, 64); s2[mt][rg] += __shfl_xor(s2[mt][rg], 2, 64);
                s2[mt][rg] += __shfl_xor(s2[mt][rg], 4, 64); s2[mt][rg] += __shfl_xor(s2[mt][rg], 8, 64);
            }
        if (ln15 == 0) {
#pragma unroll
            for (int mt = 0; mt < 4; ++mt)
#pragma unroll
                for (int rg = 0; rg < 4; ++rg) {
                    atomicAdd(&sred[mt * 16 + quad * 4 + rg], s[mt][rg]);
                    atomicAdd(&s2red[mt * 16 + quad * 4 + rg], s2[mt][rg]);
                }
        }
        __syncthreads();
        if (tid < 64) {
            unsafeAtomicAdd(&stats[rep + 128 + tid], sred[tid]);
            unsafeAtomicAdd(&stats[rep + 192 + tid], s2red[tid]);
        }
    }
    gridbar(&bar[2], &bar[3]);

    // ===================== phase 2: conv2 (64 -> 128) + row max/min ======
    if (tid < 64) {
        float ssum = 0.f, qsum = 0.f;
#pragma unroll
        for (int r = 0; r < NREP; ++r) {
            ssum += aload(&stats[r * 512 + 128 + tid]);
            qsum += aload(&stats[r * 512 + 192 + tid]);
        }
        const float mean = ssum * (1.f / NTOTF);
        const float var  = qsum * (1.f / NTOTF) - mean * mean;
        const float a    = g1[tid] / sqrtf(var + EPSF);
        als[tid] = a; bls[tid] = be1[tid] - mean * a;
    }
    if (tid < 128) { sred[tid] = 0.f; s2red[tid] = 0.f; }
    __syncthreads();

    {
        half2v ba2[8], bb2[8];
#pragma unroll
        for (int kh = 0; kh < 2; ++kh)
#pragma unroll
            for (int j2 = 0; j2 < 4; ++j2) {
                const int c0 = kh * 32 + quad * 8 + 2 * j2;
                half2v av = {(_Float16)als[c0], (_Float16)als[c0 + 1]};
                half2v bv = {(_Float16)bls[c0], (_Float16)bls[c0 + 1]};
                ba2[kh * 4 + j2] = av; bb2[kh * 4 + j2] = bv;
            }

        const int chHalf = (wid & 1) * 64;
        half8 bfr[8];
        float biasn[4];
#pragma unroll
        for (int nt = 0; nt < 4; ++nt) {
            const int n = chHalf + nt * 16 + ln15;
            biasn[nt] = cb2[n];
#pragma unroll
            for (int kh = 0; kh < 2; ++kh) {
                f32x4 wa = *reinterpret_cast<const f32x4*>(&w2[(size_t)n * 64 + kh * 32 + quad * 8]);
                f32x4 wb = *reinterpret_cast<const f32x4*>(&w2[(size_t)n * 64 + kh * 32 + quad * 8 + 4]);
                H8 t;
                t.v2[0] = cvt2(wa[0], wa[1]);
                t.v2[1] = cvt2(wa[2], wa[3]);
                t.v2[2] = cvt2(wb[0], wb[1]);
                t.v2[3] = cvt2(wb[2], wb[3]);
                bfr[nt * 2 + kh] = t.v8;
            }
        }

        float s[4] = {0, 0, 0, 0}, s2[4] = {0, 0, 0, 0};
        for (int it = 0; it < 8; ++it) {
            for (int rr = 0; rr < 2; ++rr) {
                const int rl   = it * 4 + (wid >> 1) * 2 + rr;     // 0..31
                const int prow = blk * 32 + rl;
                float mx[4] = {-3.4e38f, -3.4e38f, -3.4e38f, -3.4e38f};
                float mn[4] = {3.4e38f, 3.4e38f, 3.4e38f, 3.4e38f};
#pragma unroll 2
                for (int mt = 0; mt < 4; ++mt) {
                    const size_t rowb = (size_t)(prow * 64 + mt * 16 + ln15) * 64;
                    H8 r0f, r1f;
                    r0f.v8 = *reinterpret_cast<const half8*>(&Hin[rowb + quad * 8]);
                    r1f.v8 = *reinterpret_cast<const half8*>(&Hin[rowb + 32 + quad * 8]);
                    H8 f0, f1;
#pragma unroll
                    for (int j2 = 0; j2 < 4; ++j2) {
                        f0.v2[j2] = bn2(r0f.v2[j2], ba2[j2], bb2[j2]);
                        f1.v2[j2] = bn2(r1f.v2[j2], ba2[4 + j2], bb2[4 + j2]);
                    }
#pragma unroll
                    for (int nt = 0; nt < 4; ++nt) {
                        floatx4 a = {biasn[nt], biasn[nt], biasn[nt], biasn[nt]};
                        a = __builtin_amdgcn_mfma_f32_16x16x32_f16(f0.v8, bfr[nt * 2 + 0], a, 0, 0, 0);
                        a = __builtin_amdgcn_mfma_f32_16x16x32_f16(f1.v8, bfr[nt * 2 + 1], a, 0, 0, 0);
#pragma unroll
                        for (int rg = 0; rg < 4; ++rg) {
                            const float h = a[rg];
                            mx[nt] = fmaxf(mx[nt], h);
                            mn[nt] = fminf(mn[nt], h);
                            s[nt] += h; s2[nt] += h * h;
                        }
                    }
                }
#pragma unroll
                for (int nt = 0; nt < 4; ++nt) {
                    mx[nt] = fmaxf(mx[nt], __shfl_xor(mx[nt], 16, 64));
                    mx[nt] = fmaxf(mx[nt], __shfl_xor(mx[nt], 32, 64));
                    mn[nt] = fminf(mn[nt], __shfl_xor(mn[nt], 16, 64));
                    mn[nt] = fminf(mn[nt], __shfl_xor(mn[nt], 32, 64));
                }
                if (lane < 16) {
#pragma unroll
                    for (int nt = 0; nt < 4; ++nt) {
                        smx[rl * 128 + chHalf + nt * 16 + lane] = mx[nt];
                        smn[rl * 128 + chHalf + nt * 16 + lane] = mn[nt];
                    }
                }
            }
        }
#pragma unroll
        for (int nt = 0; nt < 4; ++nt) {
            s[nt]  += __shfl_xor(s[nt], 16, 64);  s[nt]  += __shfl_xor(s[nt], 32, 64);
            s2[nt] += __shfl_xor(s2[nt], 16, 64); s2[nt] += __shfl_xor(s2[nt], 32, 64);
        }
        if (lane < 16) {
#pragma unroll
            for (int nt = 0; nt < 4; ++nt) {
                atomicAdd(&sred[chHalf + nt * 16 + ln15], s[nt]);
                atomicAdd(&s2red[chHalf + nt * 16 + ln15], s2[nt]);
            }
        }
        __syncthreads();
        if (tid < 128) {
            unsafeAtomicAdd(&stats[rep + 256 + tid], sred[tid]);
            unsafeAtomicAdd(&stats[rep + 384 + tid], s2red[tid]);
        }
    }
    gridbar(&bar[4], &bar[5]);

    // ===================== phase 3: BN2 + epilogue =======================
    if (tid < 128) {
        float ssum = 0.f, qsum = 0.f;
#pragma unroll
        for (int r = 0; r < NREP; ++r) {
            ssum += aload(&stats[r * 512 + 256 + tid]);
            qsum += aload(&stats[r * 512 + 384 + tid]);
        }
        const float mean = ssum * (1.f / NTOTF);
        const float var  = qsum * (1.f / NTOTF) - mean * mean;
        const float a    = g2[tid] / sqrtf(var + EPSF);
        als[tid] = a; bls[tid] = be2[tid] - mean * a;
    }
    __syncthreads();

#pragma unroll
    for (int j = 0; j < 16; ++j) {
        const int local = j * 256 + tid;         // 0..4095 within block
        const int ch = local & 127;
        const float a = als[ch];
        const float v = (a > 0.f) ? smx[local] : smn[local];
        out[(size_t)blk * 4096 + local] = relu_f(a * v + bls[ch]);
    }
}

// ---------------------------------------------------------------------------
extern "C" void kernel_launch(void* const* d_in, const int* in_sizes, int n_in,
                              void* d_out, int out_size, void* d_ws, size_t ws_size,
                              hipStream_t stream)
{
    (void)in_sizes; (void)n_in; (void)out_size; (void)ws_size;
    const float* X   = (const float*)d_in[0];
    const float* w0  = (const float*)d_in[1];
    const float* b0  = (const float*)d_in[2];
    const float* g0  = (const float*)d_in[3];
    const float* be0 = (const float*)d_in[4];
    const float* w1  = (const float*)d_in[5];
    const float* b1  = (const float*)d_in[6];
    const float* g1  = (const float*)d_in[7];
    const float* be1 = (const float*)d_in[8];
    const float* w2  = (const float*)d_in[9];
    const float* b2  = (const float*)d_in[10];
    const float* g2  = (const float*)d_in[11];
    const float* be2 = (const float*)d_in[12];
    float* out = (float*)d_out;

    char* ws = (char*)d_ws;
    _Float16* H = (_Float16*)ws;                             // 134,217,728 B
    float* stats = (float*)(ws + 134217728);                 // NREP*512 floats
    unsigned int* bar = (unsigned int*)(stats + NREP * 512); // 6 uints (cnt/flg x3)

    // zero stats + barrier state each graph replay (runs before the kernel)
    hipMemsetAsync(stats, 0, (NREP * 512 + 16) * sizeof(float), stream);
    hipLaunchKernelGGL(k_fused, dim3(NBLK), dim3(256), 0, stream,
                       X, w0, b0, g0, be0, w1, b1, g1, be1, w2, b2, g2, be2,
                       H, H, stats, bar, out);
}

// Round 5
// 585.569 us; speedup vs baseline: 1.4200x; 1.4200x over previous
//
#include <hip/hip_runtime.h>

#define ROWS  16384
#define PTOT  1048576
#define NTOTF 1048576.0f
#define EPSF  1e-5f
#define NREP  16                 // stats replication factor (atomic decontention)

typedef _Float16 half8  __attribute__((ext_vector_type(8)));   // MFMA A/B frag (4 VGPR)
typedef _Float16 half2v __attribute__((ext_vector_type(2)));
typedef __fp16   fp16x2 __attribute__((ext_vector_type(2)));   // cvt_pkrtz result type
typedef __attribute__((ext_vector_type(4))) float floatx4;     // MFMA C/D frag
typedef float f32x4 __attribute__((ext_vector_type(4)));
typedef f32x4 f32x4u __attribute__((aligned(4)));              // 4B-aligned vector load

union H8 { half8 v8; half2v v2[4]; };
union PK2 { fp16x2 p; half2v h; unsigned int u; };

__device__ __forceinline__ half2v cvt2(float lo, float hi) {
    PK2 k; k.p = __builtin_amdgcn_cvt_pkrtz(lo, hi); return k.h;
}
__device__ __forceinline__ unsigned int cvt2u(float lo, float hi) {
    PK2 k; k.p = __builtin_amdgcn_cvt_pkrtz(lo, hi); return k.u;
}
__device__ __forceinline__ float relu_f(float x) { return x > 0.f ? x : 0.f; }

__device__ __forceinline__ half8 h8zero() {
    half8 z = {(_Float16)0.f, (_Float16)0.f, (_Float16)0.f, (_Float16)0.f,
               (_Float16)0.f, (_Float16)0.f, (_Float16)0.f, (_Float16)0.f};
    return z;
}

// packed BN + ReLU: v_pk_fma_f16 + v_pk_max_f16
__device__ __forceinline__ half2v bn2(half2v h, half2v a, half2v b) {
    half2v z = {(_Float16)0.f, (_Float16)0.f};
    return __builtin_elementwise_max((half2v)(h * a + b), z);
}

// async global->LDS DMA, 16B per lane: LDS dest = uniform base + lane*16,
// global src = per-lane address.
typedef const __attribute__((address_space(1))) unsigned int* gas1;
typedef __attribute__((address_space(3))) unsigned int* las3;
__device__ __forceinline__ void gl16(const void* g, void* l) {
    __builtin_amdgcn_global_load_lds((gas1)(unsigned long long)g,
                                     (las3)(unsigned int)(unsigned long long)l,
                                     16, 0, 0);
}
// counted vmcnt wait; sched_barrier stops hipcc hoisting LDS reads above it
#define WVM(N) { asm volatile("s_waitcnt vmcnt(" #N ")" ::: "memory"); __builtin_amdgcn_sched_barrier(0); }
// order pin: the vmcnt counting model requires the DMA groups to ISSUE in
// source order; without this the scheduler may interleave stage(0)/stage(1)
// (round-4 failure). Entry pin also keeps each stage after the previous
// compute's (lgkmcnt-complete) LDS reads -> no WAR on the recycled buffer.
#define SB __builtin_amdgcn_sched_barrier(0)

// ---------------------------------------------------------------------------
// K1: conv0  X[P][67] fp32 -> H[P][64] fp16.  Per-wave 16-row X tiles
// (4288 B contiguous) staged via global_load_lds (4 full 1KB calls + one
// 12-lane call), double-buffered, counted vmcnt. Odd 268B row stride spreads
// LDS banks naturally. MFMA as before (A=w0 persistent, B=positions).
// ---------------------------------------------------------------------------
__global__ __launch_bounds__(256) void k_conv0(
    const float* __restrict__ X, const float* __restrict__ w0,
    const float* __restrict__ b0, _Float16* __restrict__ H,
    float* __restrict__ stats)
{
    __shared__ float sred[64], s2red[64];
    __shared__ __align__(16) char xbuf[4][2][4352];
    const int tid  = threadIdx.x;
    const int lane = tid & 63;
    const int wid  = tid >> 6;
    const int ln15 = lane & 15;
    const int quad = lane >> 4;
    const int pbase = blockIdx.x * 256 + wid * 64;

    if (tid < 64) { sred[tid] = 0.f; s2red[tid] = 0.f; }
    __syncthreads();

    // A-fragments: weights. m = mt*16+ln15, k = kh*32+quad*8+j (+ tail frag)
    half8 afr[4][3];
    floatx4 bias[4];
#pragma unroll
    for (int mt = 0; mt < 4; ++mt) {
        const float* wr = w0 + (size_t)(mt * 16 + ln15) * 67;
#pragma unroll
        for (int kh = 0; kh < 2; ++kh) {
            f32x4u wa = *reinterpret_cast<const f32x4u*>(wr + kh * 32 + quad * 8);
            f32x4u wb = *reinterpret_cast<const f32x4u*>(wr + kh * 32 + quad * 8 + 4);
            H8 t;
            t.v2[0] = cvt2(wa[0], wa[1]);
            t.v2[1] = cvt2(wa[2], wa[3]);
            t.v2[2] = cvt2(wb[0], wb[1]);
            t.v2[3] = cvt2(wb[2], wb[3]);
            afr[mt][kh] = t.v8;
        }
        H8 t; t.v8 = h8zero();
        if (quad == 0) {
            f32x4u tv = *reinterpret_cast<const f32x4u*>(wr + 63);  // cols 63..66
            t.v2[0] = cvt2(tv[1], tv[2]);
            t.v2[1] = cvt2(tv[3], 0.f);
        }
        afr[mt][2] = t.v8;
        bias[mt] = *reinterpret_cast<const floatx4*>(b0 + mt * 16 + quad * 4);
    }

    float s[4][4] = {}, s2[4][4] = {};

    auto stage = [&](int nt) {
        SB;
        const char* src = (const char*)X + (size_t)(pbase + nt * 16) * 268;
        char* dst = &xbuf[wid][nt & 1][0];
#pragma unroll
        for (int c = 0; c < 4; ++c)
            gl16(src + c * 1024 + lane * 16, dst + c * 1024);
        if (lane < 12) gl16(src + 4096 + lane * 16, dst + 4096);  // tail 192 B
        SB;
    };
    auto compute = [&](int nt) {
        const char* tb = &xbuf[wid][nt & 1][0];
        const float* xr = (const float*)(tb + ln15 * 268);
        const int pos = pbase + nt * 16 + ln15;
        H8 B0, B1, BT;
        {
            f32x4u xa = *reinterpret_cast<const f32x4u*>(xr + quad * 8);
            f32x4u xb = *reinterpret_cast<const f32x4u*>(xr + quad * 8 + 4);
            f32x4u xc = *reinterpret_cast<const f32x4u*>(xr + 32 + quad * 8);
            f32x4u xd = *reinterpret_cast<const f32x4u*>(xr + 32 + quad * 8 + 4);
            B0.v2[0] = cvt2(xa[0], xa[1]);
            B0.v2[1] = cvt2(xa[2], xa[3]);
            B0.v2[2] = cvt2(xb[0], xb[1]);
            B0.v2[3] = cvt2(xb[2], xb[3]);
            B1.v2[0] = cvt2(xc[0], xc[1]);
            B1.v2[1] = cvt2(xc[2], xc[3]);
            B1.v2[2] = cvt2(xd[0], xd[1]);
            B1.v2[3] = cvt2(xd[2], xd[3]);
            BT.v8 = h8zero();
            if (quad == 0) {
                const float* tf = xr + 63;
                BT.v2[0] = cvt2(tf[1], tf[2]);
                BT.v2[1] = cvt2(tf[3], 0.f);
            }
        }
#pragma unroll
        for (int mt = 0; mt < 4; ++mt) {
            floatx4 c = bias[mt];
            c = __builtin_amdgcn_mfma_f32_16x16x32_f16(afr[mt][0], B0.v8, c, 0, 0, 0);
            c = __builtin_amdgcn_mfma_f32_16x16x32_f16(afr[mt][1], B1.v8, c, 0, 0, 0);
            c = __builtin_amdgcn_mfma_f32_16x16x32_f16(afr[mt][2], BT.v8, c, 0, 0, 0);
            s[mt][0] += c[0]; s2[mt][0] += c[0] * c[0];
            s[mt][1] += c[1]; s2[mt][1] += c[1] * c[1];
            s[mt][2] += c[2]; s2[mt][2] += c[2] * c[2];
            s[mt][3] += c[3]; s2[mt][3] += c[3] * c[3];
            uint2 o;
            o.x = cvt2u(c[0], c[1]);
            o.y = cvt2u(c[2], c[3]);
            *reinterpret_cast<uint2*>(&H[(size_t)pos * 64 + mt * 16 + quad * 4]) = o;
        }
    };

    // pipeline: S0 S1 W(5) C0 | S2 W(9) C1 | S3 W(9) C2 | W(4) C3
    stage(0); stage(1);
    WVM(5);  compute(0);
    stage(2);
    WVM(9);  compute(1);
    stage(3);
    WVM(9);  compute(2);
    WVM(4);  compute(3);

#pragma unroll
    for (int mt = 0; mt < 4; ++mt)
#pragma unroll
        for (int rg = 0; rg < 4; ++rg) {
            s[mt][rg]  += __shfl_xor(s[mt][rg], 1, 64);  s[mt][rg]  += __shfl_xor(s[mt][rg], 2, 64);
            s[mt][rg]  += __shfl_xor(s[mt][rg], 4, 64);  s[mt][rg]  += __shfl_xor(s[mt][rg], 8, 64);
            s2[mt][rg] += __shfl_xor(s2[mt][rg], 1, 64); s2[mt][rg] += __shfl_xor(s2[mt][rg], 2, 64);
            s2[mt][rg] += __shfl_xor(s2[mt][rg], 4, 64); s2[mt][rg] += __shfl_xor(s2[mt][rg], 8, 64);
        }
    if (ln15 == 0) {
#pragma unroll
        for (int mt = 0; mt < 4; ++mt)
#pragma unroll
            for (int rg = 0; rg < 4; ++rg) {
                atomicAdd(&sred[mt * 16 + quad * 4 + rg], s[mt][rg]);
                atomicAdd(&s2red[mt * 16 + quad * 4 + rg], s2[mt][rg]);
            }
    }
    __syncthreads();
    const int rep = (blockIdx.x & (NREP - 1)) * 512;
    if (tid < 64) {
        unsafeAtomicAdd(&stats[rep + tid], sred[tid]);
        unsafeAtomicAdd(&stats[rep + 64 + tid], s2red[tid]);
    }
}

// ---------------------------------------------------------------------------
// K2: conv1 64->64. 16-row H tiles (2048 B) staged via 2 gl16 calls,
// double-buffered, XOR-16 swizzle (stride-128B rows are otherwise a 16-way
// bank conflict): source address pre-swizzled, reads use the same XOR
// (both-sides-or-neither). BN0+relu packed fp16 in registers.
// ---------------------------------------------------------------------------
__global__ __launch_bounds__(256) void k_conv1(
    const _Float16* __restrict__ Hin, _Float16* __restrict__ Hout,
    const float* __restrict__ w1, const float* __restrict__ b1,
    const float* __restrict__ g0, const float* __restrict__ be0,
    float* __restrict__ stats)
{
    __shared__ float als[64], bls[64], sred[64], s2red[64];
    __shared__ __align__(16) char hbuf[4][2][2048];
    const int tid  = threadIdx.x;
    const int lane = tid & 63;
    const int wid  = tid >> 6;
    const int ln15 = lane & 15;
    const int quad = lane >> 4;
    const int pbase = blockIdx.x * 256 + wid * 64;
    const int swl = (((lane & 7) ^ (lane >> 3)) << 4);   // stage-side swizzle

    if (tid < 64) {
        float ssum = 0.f, qsum = 0.f;
#pragma unroll
        for (int r = 0; r < NREP; ++r) { ssum += stats[r * 512 + tid]; qsum += stats[r * 512 + 64 + tid]; }
        const float mean = ssum * (1.f / NTOTF);
        const float var  = qsum * (1.f / NTOTF) - mean * mean;
        const float a    = g0[tid] / sqrtf(var + EPSF);
        als[tid] = a; bls[tid] = be0[tid] - mean * a;
        sred[tid] = 0.f; s2red[tid] = 0.f;
    }
    __syncthreads();

    half2v ba2[8], bb2[8];
#pragma unroll
    for (int kh = 0; kh < 2; ++kh)
#pragma unroll
        for (int j2 = 0; j2 < 4; ++j2) {
            const int c0 = kh * 32 + quad * 8 + 2 * j2;
            half2v av = {(_Float16)als[c0], (_Float16)als[c0 + 1]};
            half2v bv = {(_Float16)bls[c0], (_Float16)bls[c0 + 1]};
            ba2[kh * 4 + j2] = av; bb2[kh * 4 + j2] = bv;
        }

    half8 afr[4][2];
    floatx4 bias[4];
#pragma unroll
    for (int mt = 0; mt < 4; ++mt) {
        const float* wr = w1 + (size_t)(mt * 16 + ln15) * 64;
#pragma unroll
        for (int kh = 0; kh < 2; ++kh) {
            f32x4 wa = *reinterpret_cast<const f32x4*>(wr + kh * 32 + quad * 8);
            f32x4 wb = *reinterpret_cast<const f32x4*>(wr + kh * 32 + quad * 8 + 4);
            H8 t;
            t.v2[0] = cvt2(wa[0], wa[1]);
            t.v2[1] = cvt2(wa[2], wa[3]);
            t.v2[2] = cvt2(wb[0], wb[1]);
            t.v2[3] = cvt2(wb[2], wb[3]);
            afr[mt][kh] = t.v8;
        }
        bias[mt] = *reinterpret_cast<const floatx4*>(b1 + mt * 16 + quad * 4);
    }

    float s[4][4] = {}, s2[4][4] = {};

    auto stage = [&](int nt) {
        SB;
        const char* base = (const char*)Hin + (size_t)(pbase + nt * 16) * 128;
        char* dst = &hbuf[wid][nt & 1][0];
#pragma unroll
        for (int c = 0; c < 2; ++c)
            gl16(base + c * 1024 + (lane >> 3) * 128 + swl, dst + c * 1024);
        SB;
    };
    auto compute = [&](int nt) {
        const char* tb = &hbuf[wid][nt & 1][0];
        const half8* rowp = (const half8*)(tb + ln15 * 128);
        const int pos = pbase + nt * 16 + ln15;
        H8 r0, r1;
        r0.v8 = rowp[quad ^ (ln15 & 7)];
        r1.v8 = rowp[(4 + quad) ^ (ln15 & 7)];
        H8 f0, f1;
#pragma unroll
        for (int j2 = 0; j2 < 4; ++j2) {
            f0.v2[j2] = bn2(r0.v2[j2], ba2[j2], bb2[j2]);
            f1.v2[j2] = bn2(r1.v2[j2], ba2[4 + j2], bb2[4 + j2]);
        }
#pragma unroll
        for (int mt = 0; mt < 4; ++mt) {
            floatx4 c = bias[mt];
            c = __builtin_amdgcn_mfma_f32_16x16x32_f16(afr[mt][0], f0.v8, c, 0, 0, 0);
            c = __builtin_amdgcn_mfma_f32_16x16x32_f16(afr[mt][1], f1.v8, c, 0, 0, 0);
            s[mt][0] += c[0]; s2[mt][0] += c[0] * c[0];
            s[mt][1] += c[1]; s2[mt][1] += c[1] * c[1];
            s[mt][2] += c[2]; s2[mt][2] += c[2] * c[2];
            s[mt][3] += c[3]; s2[mt][3] += c[3] * c[3];
            uint2 o;
            o.x = cvt2u(c[0], c[1]);
            o.y = cvt2u(c[2], c[3]);
            *reinterpret_cast<uint2*>(&Hout[(size_t)pos * 64 + mt * 16 + quad * 4]) = o;
        }
    };

    // pipeline: S0 S1 W(2) C0 | S2 W(6) C1 | S3 W(6) C2 | W(4) C3
    stage(0); stage(1);
    WVM(2);  compute(0);
    stage(2);
    WVM(6);  compute(1);
    stage(3);
    WVM(6);  compute(2);
    WVM(4);  compute(3);

#pragma unroll
    for (int mt = 0; mt < 4; ++mt)
#pragma unroll
        for (int rg = 0; rg < 4; ++rg) {
            s[mt][rg]  += __shfl_xor(s[mt][rg], 1, 64);  s[mt][rg]  += __shfl_xor(s[mt][rg], 2, 64);
            s[mt][rg]  += __shfl_xor(s[mt][rg], 4, 64);  s[mt][rg]  += __shfl_xor(s[mt][rg], 8, 64);
            s2[mt][rg] += __shfl_xor(s2[mt][rg], 1, 64); s2[mt][rg] += __shfl_xor(s2[mt][rg], 2, 64);
            s2[mt][rg] += __shfl_xor(s2[mt][rg], 4, 64); s2[mt][rg] += __shfl_xor(s2[mt][rg], 8, 64);
        }
    if (ln15 == 0) {
#pragma unroll
        for (int mt = 0; mt < 4; ++mt)
#pragma unroll
            for (int rg = 0; rg < 4; ++rg) {
                atomicAdd(&sred[mt * 16 + quad * 4 + rg], s[mt][rg]);
                atomicAdd(&s2red[mt * 16 + quad * 4 + rg], s2[mt][rg]);
            }
    }
    __syncthreads();
    const int rep = (blockIdx.x & (NREP - 1)) * 512;
    if (tid < 64) {
        unsafeAtomicAdd(&stats[rep + 128 + tid], sred[tid]);
        unsafeAtomicAdd(&stats[rep + 192 + tid], s2red[tid]);
    }
}

// ---------------------------------------------------------------------------
// K3: conv2 64->128 (A = data orientation). Same 16-row staged tiles as K2
// (8 tiles per wave, double-buffered). Packed BN1+relu; max/min monotone-BN
// trick; bias in MFMA C-init; stats replicated.
// ---------------------------------------------------------------------------
__global__ __launch_bounds__(256) void k_conv2(
    const _Float16* __restrict__ H, const float* __restrict__ w2,
    const float* __restrict__ b2c, const float* __restrict__ g1,
    const float* __restrict__ be1, float* __restrict__ rowmax,
    float* __restrict__ rowmin, float* __restrict__ stats)
{
    __shared__ float als[64], bls[64], sred[128], s2red[128];
    __shared__ __align__(16) char vbuf[4][2][2048];
    const int tid  = threadIdx.x;
    const int lane = tid & 63;
    const int wid  = tid >> 6;
    const int ln15 = lane & 15;
    const int quad = lane >> 4;
    const int r0   = blockIdx.x * 4;
    const int swl  = (((lane & 7) ^ (lane >> 3)) << 4);

    if (tid < 64) {
        float ssum = 0.f, qsum = 0.f;
#pragma unroll
        for (int r = 0; r < NREP; ++r) { ssum += stats[r * 512 + 128 + tid]; qsum += stats[r * 512 + 192 + tid]; }
        const float mean = ssum * (1.f / NTOTF);
        const float var  = qsum * (1.f / NTOTF) - mean * mean;
        const float a    = g1[tid] / sqrtf(var + EPSF);
        als[tid] = a; bls[tid] = be1[tid] - mean * a;
    }
    if (tid < 128) { sred[tid] = 0.f; s2red[tid] = 0.f; }
    __syncthreads();

    half2v ba2[8], bb2[8];
#pragma unroll
    for (int kh = 0; kh < 2; ++kh)
#pragma unroll
        for (int j2 = 0; j2 < 4; ++j2) {
            const int c0 = kh * 32 + quad * 8 + 2 * j2;
            half2v av = {(_Float16)als[c0], (_Float16)als[c0 + 1]};
            half2v bv = {(_Float16)bls[c0], (_Float16)bls[c0 + 1]};
            ba2[kh * 4 + j2] = av; bb2[kh * 4 + j2] = bv;
        }

    const int chHalf = (wid & 1) * 64;
    half8 bfr[8];
    float biasn[4];
#pragma unroll
    for (int nt = 0; nt < 4; ++nt) {
        const int n = chHalf + nt * 16 + ln15;
        biasn[nt] = b2c[n];
#pragma unroll
        for (int kh = 0; kh < 2; ++kh) {
            f32x4 wa = *reinterpret_cast<const f32x4*>(&w2[(size_t)n * 64 + kh * 32 + quad * 8]);
            f32x4 wb = *reinterpret_cast<const f32x4*>(&w2[(size_t)n * 64 + kh * 32 + quad * 8 + 4]);
            H8 t;
            t.v2[0] = cvt2(wa[0], wa[1]);
            t.v2[1] = cvt2(wa[2], wa[3]);
            t.v2[2] = cvt2(wb[0], wb[1]);
            t.v2[3] = cvt2(wb[2], wb[3]);
            bfr[nt * 2 + kh] = t.v8;
        }
    }

    const int prowbase = r0 + (wid >> 1) * 2;
    auto stage = [&](int t) {   // t = rr*4 + mt
        SB;
        const char* base = (const char*)H +
            (size_t)((prowbase + (t >> 2)) * 64 + (t & 3) * 16) * 128;
        char* dst = &vbuf[wid][t & 1][0];
#pragma unroll
        for (int c = 0; c < 2; ++c)
            gl16(base + c * 1024 + (lane >> 3) * 128 + swl, dst + c * 1024);
        SB;
    };

    float s[4] = {0, 0, 0, 0}, s2[4] = {0, 0, 0, 0};
    stage(0);
#pragma unroll
    for (int rr = 0; rr < 2; ++rr) {
        const int prow = prowbase + rr;
        float mx[4] = {-3.4e38f, -3.4e38f, -3.4e38f, -3.4e38f};
        float mn[4] = {3.4e38f, 3.4e38f, 3.4e38f, 3.4e38f};
#pragma unroll
        for (int mt = 0; mt < 4; ++mt) {
            const int t = rr * 4 + mt;
            if (t < 7) stage(t + 1);
            if (t == 7) { WVM(0); } else { WVM(2); }
            const char* tb = &vbuf[wid][t & 1][0];
            const half8* rowp = (const half8*)(tb + ln15 * 128);
            H8 r0f, r1f;
            r0f.v8 = rowp[quad ^ (ln15 & 7)];
            r1f.v8 = rowp[(4 + quad) ^ (ln15 & 7)];
            H8 f0, f1;
#pragma unroll
            for (int j2 = 0; j2 < 4; ++j2) {
                f0.v2[j2] = bn2(r0f.v2[j2], ba2[j2], bb2[j2]);
                f1.v2[j2] = bn2(r1f.v2[j2], ba2[4 + j2], bb2[4 + j2]);
            }
#pragma unroll
            for (int nt = 0; nt < 4; ++nt) {
                floatx4 a = {biasn[nt], biasn[nt], biasn[nt], biasn[nt]};
                a = __builtin_amdgcn_mfma_f32_16x16x32_f16(f0.v8, bfr[nt * 2 + 0], a, 0, 0, 0);
                a = __builtin_amdgcn_mfma_f32_16x16x32_f16(f1.v8, bfr[nt * 2 + 1], a, 0, 0, 0);
#pragma unroll
                for (int rg = 0; rg < 4; ++rg) {
                    const float h = a[rg];
                    mx[nt] = fmaxf(mx[nt], h);
                    mn[nt] = fminf(mn[nt], h);
                    s[nt] += h; s2[nt] += h * h;
                }
            }
        }
#pragma unroll
        for (int nt = 0; nt < 4; ++nt) {
            mx[nt] = fmaxf(mx[nt], __shfl_xor(mx[nt], 16, 64));
            mx[nt] = fmaxf(mx[nt], __shfl_xor(mx[nt], 32, 64));
            mn[nt] = fminf(mn[nt], __shfl_xor(mn[nt], 16, 64));
            mn[nt] = fminf(mn[nt], __shfl_xor(mn[nt], 32, 64));
        }
        if (lane < 16) {
#pragma unroll
            for (int nt = 0; nt < 4; ++nt) {
                rowmax[(size_t)prow * 128 + chHalf + nt * 16 + lane] = mx[nt];
                rowmin[(size_t)prow * 128 + chHalf + nt * 16 + lane] = mn[nt];
            }
        }
    }
#pragma unroll
    for (int nt = 0; nt < 4; ++nt) {
        s[nt]  += __shfl_xor(s[nt], 16, 64);  s[nt]  += __shfl_xor(s[nt], 32, 64);
        s2[nt] += __shfl_xor(s2[nt], 16, 64); s2[nt] += __shfl_xor(s2[nt], 32, 64);
    }
    if (lane < 16) {
#pragma unroll
        for (int nt = 0; nt < 4; ++nt) {
            atomicAdd(&sred[chHalf + nt * 16 + ln15], s[nt]);
            atomicAdd(&s2red[chHalf + nt * 16 + ln15], s2[nt]);
        }
    }
    __syncthreads();
    const int rep = (blockIdx.x & (NREP - 1)) * 512;
    if (tid < 128) {
        unsafeAtomicAdd(&stats[rep + 256 + tid], sred[tid]);
        unsafeAtomicAdd(&stats[rep + 384 + tid], s2red[tid]);
    }
}

// ---------------------------------------------------------------------------
// K4: finalize BN2 + epilogue
// ---------------------------------------------------------------------------
__global__ __launch_bounds__(256) void k_out(
    const float* __restrict__ rowmax, const float* __restrict__ rowmin,
    const float* __restrict__ g2, const float* __restrict__ be2,
    const float* __restrict__ stats, float* __restrict__ out)
{
    __shared__ float als[128], bls[128];
    const int tid = threadIdx.x;
    if (tid < 128) {
        float ssum = 0.f, qsum = 0.f;
#pragma unroll
        for (int r = 0; r < NREP; ++r) { ssum += stats[r * 512 + 256 + tid]; qsum += stats[r * 512 + 384 + tid]; }
        const float mean = ssum * (1.f / NTOTF);
        const float var  = qsum * (1.f / NTOTF) - mean * mean;
        const float a    = g2[tid] / sqrtf(var + EPSF);
        als[tid] = a; bls[tid] = be2[tid] - mean * a;
    }
    __syncthreads();
    const int idx = blockIdx.x * 256 + tid;
    const int o = idx & 127;
    const float a = als[o];
    const float v = (a > 0.f) ? rowmax[idx] : rowmin[idx];
    out[idx] = relu_f(a * v + bls[o]);
}

// ---------------------------------------------------------------------------
extern "C" void kernel_launch(void* const* d_in, const int* in_sizes, int n_in,
                              void* d_out, int out_size, void* d_ws, size_t ws_size,
                              hipStream_t stream)
{
    (void)in_sizes; (void)n_in; (void)out_size; (void)ws_size;
    const float* X   = (const float*)d_in[0];
    const float* w0  = (const float*)d_in[1];
    const float* b0  = (const float*)d_in[2];
    const float* g0  = (const float*)d_in[3];
    const float* be0 = (const float*)d_in[4];
    const float* w1  = (const float*)d_in[5];
    const float* b1  = (const float*)d_in[6];
    const float* g1  = (const float*)d_in[7];
    const float* be1 = (const float*)d_in[8];
    const float* w2  = (const float*)d_in[9];
    const float* b2  = (const float*)d_in[10];
    const float* g2  = (const float*)d_in[11];
    const float* be2 = (const float*)d_in[12];
    float* out = (float*)d_out;

    char* ws = (char*)d_ws;
    _Float16* H = (_Float16*)ws;                             // 134,217,728 B
    float* rowmax = (float*)(ws + 134217728);                // 8,388,608 B
    float* rowmin = (float*)(ws + 134217728 + 8388608);      // 8,388,608 B
    float* stats  = (float*)(ws + 134217728 + 2 * 8388608);  // NREP*512 floats

    hipMemsetAsync(stats, 0, NREP * 512 * sizeof(float), stream);
    hipLaunchKernelGGL(k_conv0, dim3(PTOT / 256), dim3(256), 0, stream, X, w0, b0, H, stats);
    hipLaunchKernelGGL(k_conv1, dim3(PTOT / 256), dim3(256), 0, stream, H, H, w1, b1, g0, be0, stats);
    hipLaunchKernelGGL(k_conv2, dim3(ROWS / 4), dim3(256), 0, stream, H, w2, b2, g1, be1, rowmax, rowmin, stats);
    hipLaunchKernelGGL(k_out, dim3(ROWS * 128 / 256), dim3(256), 0, stream, rowmax, rowmin, g2, be2, stats, out);
}